// Round 4
// baseline (203.222 us; speedup 1.0000x reference)
//
#include <hip/hip_runtime.h>

// C[n][m] = A[n] * B[n][m]   (N=32768, M=4096, fp32)
// Two rows per block, 8 float4/thread. Cached (non-NT) loads — matches the
// 6.29 TB/s m13 copy pattern; NT stores only (avoid RFO / L2 write thrash).

typedef float f32x4 __attribute__((ext_vector_type(4)));

#define M_F4 1024   // 4096/4 float4s per row
#define ROWS_PER_BLOCK 2

__global__ __launch_bounds__(256) void rowscale_rows2(
    const float* __restrict__ A,
    const f32x4* __restrict__ B4,
    f32x4* __restrict__ C4)
{
    const int row0 = blockIdx.x * ROWS_PER_BLOCK;   // uniform per block
    const int t = threadIdx.x;

    const float a0 = A[row0];        // -> s_load (wave-uniform)
    const float a1 = A[row0 + 1];

    const f32x4* __restrict__ b = B4 + (size_t)row0 * M_F4;
    f32x4* __restrict__ c = C4 + (size_t)row0 * M_F4;

    f32x4 v[8];
#pragma unroll
    for (int k = 0; k < 4; ++k)
        v[k] = b[t + k * 256];
#pragma unroll
    for (int k = 0; k < 4; ++k)
        v[4 + k] = b[M_F4 + t + k * 256];

#pragma unroll
    for (int k = 0; k < 4; ++k)
        __builtin_nontemporal_store(v[k] * a0, &c[t + k * 256]);
#pragma unroll
    for (int k = 0; k < 4; ++k)
        __builtin_nontemporal_store(v[4 + k] * a1, &c[M_F4 + t + k * 256]);
}

extern "C" void kernel_launch(void* const* d_in, const int* in_sizes, int n_in,
                              void* d_out, int out_size, void* d_ws, size_t ws_size,
                              hipStream_t stream)
{
    const float* A = (const float*)d_in[0];
    const f32x4* B4 = (const f32x4*)d_in[1];
    f32x4* C4 = (f32x4*)d_out;

    const int n_rows = in_sizes[0];          // 32768
    const int grid = n_rows / ROWS_PER_BLOCK; // 16384

    rowscale_rows2<<<grid, 256, 0, stream>>>(A, B4, C4);
}

// Round 5
// 191.610 us; speedup vs baseline: 1.0606x; 1.0606x over previous
//
#include <hip/hip_runtime.h>

// C[n][m] = A[n] * B[n][m]   (N=32768, M=4096, fp32)
// Two rows per block, 8 float4/thread, NT loads AND NT stores (round-3's
// NT-both config was the winner; round-4 showed cached loads regress).

typedef float f32x4 __attribute__((ext_vector_type(4)));

#define M_F4 1024   // 4096/4 float4s per row
#define ROWS_PER_BLOCK 2

__global__ __launch_bounds__(256) void rowscale_rows2nt(
    const float* __restrict__ A,
    const f32x4* __restrict__ B4,
    f32x4* __restrict__ C4)
{
    const int row0 = blockIdx.x * ROWS_PER_BLOCK;   // uniform per block
    const int t = threadIdx.x;

    const float a0 = A[row0];        // -> s_load (wave-uniform)
    const float a1 = A[row0 + 1];

    const f32x4* __restrict__ b = B4 + (size_t)row0 * M_F4;
    f32x4* __restrict__ c = C4 + (size_t)row0 * M_F4;

    f32x4 v[8];
#pragma unroll
    for (int k = 0; k < 4; ++k)
        v[k] = __builtin_nontemporal_load(&b[t + k * 256]);
#pragma unroll
    for (int k = 0; k < 4; ++k)
        v[4 + k] = __builtin_nontemporal_load(&b[M_F4 + t + k * 256]);

#pragma unroll
    for (int k = 0; k < 4; ++k)
        __builtin_nontemporal_store(v[k] * a0, &c[t + k * 256]);
#pragma unroll
    for (int k = 0; k < 4; ++k)
        __builtin_nontemporal_store(v[4 + k] * a1, &c[M_F4 + t + k * 256]);
}

extern "C" void kernel_launch(void* const* d_in, const int* in_sizes, int n_in,
                              void* d_out, int out_size, void* d_ws, size_t ws_size,
                              hipStream_t stream)
{
    const float* A = (const float*)d_in[0];
    const f32x4* B4 = (const f32x4*)d_in[1];
    f32x4* C4 = (f32x4*)d_out;

    const int n_rows = in_sizes[0];          // 32768
    const int grid = n_rows / ROWS_PER_BLOCK; // 16384

    rowscale_rows2nt<<<grid, 256, 0, stream>>>(A, B4, C4);
}

// Round 6
// 181.177 us; speedup vs baseline: 1.1217x; 1.0576x over previous
//
#include <hip/hip_runtime.h>

// C[n][m] = A[n] * B[n][m]   (N=32768, M=4096, fp32)
// One block per row, 4 float4/thread, NT loads AND NT stores.
// R3-proven config: 180.5 us = 5.95 TB/s (94.6% of 6.29 TB/s copy ceiling).
// R4/R5 ablations: cached loads -12%, 2-rows/block -6%.

typedef float f32x4 __attribute__((ext_vector_type(4)));

#define M_F4 1024   // 4096 / 4 float4s per row

__global__ __launch_bounds__(256) void rowscale_rows(
    const float* __restrict__ A,
    const f32x4* __restrict__ B4,
    f32x4* __restrict__ C4)
{
    const int row = blockIdx.x;              // uniform per block
    const float a = A[row];                  // -> s_load (wave-uniform)

    const f32x4* __restrict__ b = B4 + (size_t)row * M_F4;
    f32x4* __restrict__ c = C4 + (size_t)row * M_F4;

    const int t = threadIdx.x;

    f32x4 v[4];
#pragma unroll
    for (int k = 0; k < 4; ++k)
        v[k] = __builtin_nontemporal_load(&b[t + k * 256]);

#pragma unroll
    for (int k = 0; k < 4; ++k)
        __builtin_nontemporal_store(v[k] * a, &c[t + k * 256]);
}

extern "C" void kernel_launch(void* const* d_in, const int* in_sizes, int n_in,
                              void* d_out, int out_size, void* d_ws, size_t ws_size,
                              hipStream_t stream)
{
    const float* A = (const float*)d_in[0];
    const f32x4* B4 = (const f32x4*)d_in[1];
    f32x4* C4 = (f32x4*)d_out;

    const int n_rows = in_sizes[0];          // 32768

    rowscale_rows<<<n_rows, 256, 0, stream>>>(A, B4, C4);
}